// Round 15
// baseline (341.413 us; speedup 1.0000x reference)
//
#include <hip/hip_runtime.h>
#include <hip/hip_fp16.h>

#define DIM 128
#define BSH 9              // dsts per bucket = 512  (NB = 196 for N=100032)
#define SC_EDGES 4096      // edges per scatter/hist block

typedef _Float16 f16x8 __attribute__((ext_vector_type(8)));
typedef float f32x4 __attribute__((ext_vector_type(4)));

// ---------------- pack W into MFMA A-fragments ----------------
// Wf[b][lane][j] = W[l][ mt*16 + (lane&15) ][ s*32 + (lane>>4)*8 + j ],  b=(l*4+s)*8+mt
__global__ __launch_bounds__(64) void pack_wf_kernel(
    const float* __restrict__ W, __half* __restrict__ Wf)
{
    const int b = blockIdx.x;
    const int mt = b & 7;
    const int s  = (b >> 3) & 3;
    const int l  = b >> 5;
    const int lane = threadIdx.x;
    const int c  = mt * 16 + (lane & 15);
    const int k0 = s * 32 + (lane >> 4) * 8;
    const float* wr = W + ((size_t)l << 14) + c * DIM + k0;
    __half* dp = Wf + ((size_t)b * 64 + lane) * 8;
    #pragma unroll
    for (int j = 0; j < 8; ++j) dp[j] = __float2half(wr[j]);
}

// ---------------- x0 = concat(row_embed, col_embed) -> fp16 ----------------
__global__ __launch_bounds__(256) void convert_x0_kernel(
    const float* __restrict__ xa, const float* __restrict__ xb,
    __half* __restrict__ xh, int nrows_a, int N)
{
    const int i = blockIdx.x * 256 + threadIdx.x;
    if (i >= N * (DIM / 4)) return;
    const int row = i >> 5;
    const int g = i & 31;
    const float* sp = (row < nrows_a) ? xa + (size_t)row * DIM
                                      : xb + (size_t)(row - nrows_a) * DIM;
    const float4 v = ((const float4*)sp)[g];
    __half2* dp = (__half2*)(xh + (size_t)row * DIM + g * 4);
    dp[0] = __floats2half2_rn(v.x, v.y);
    dp[1] = __floats2half2_rn(v.z, v.w);
}

__global__ __launch_bounds__(256) void zero_i_kernel(int* __restrict__ p, int n)
{
    const int i = blockIdx.x * 256 + threadIdx.x;
    if (i < n) p[i] = 0;
}

// ---------------- bucket histogram: LDS pre-aggregation ----------------------
__global__ __launch_bounds__(256) void hist_block_kernel(
    const int* __restrict__ ei, int* __restrict__ hist, int E)
{
    __shared__ int cnt[256];
    const int tid = threadIdx.x;
    cnt[tid] = 0;
    __syncthreads();
    const int base = blockIdx.x * SC_EDGES;
    #pragma unroll
    for (int k = 0; k < 16; ++k) {
        const int e = base + k * 256 + tid;
        if (e < E) atomicAdd(&cnt[ei[E + e] >> BSH], 1);
    }
    __syncthreads();
    if (cnt[tid] > 0) atomicAdd(&hist[tid], cnt[tid]);
}

// ---------------- exclusive scan of NB (<=256) bucket counts -----------------
__global__ __launch_bounds__(256) void scan_nb_kernel(
    const int* __restrict__ hist, int* __restrict__ segStart,
    int* __restrict__ bucketCur, int NB, int E)
{
    __shared__ int tsum[256];
    const int tid = threadIdx.x;
    const int c = (tid < NB) ? hist[tid] : 0;
    tsum[tid] = c;
    __syncthreads();
    int x = c;
    for (int off = 1; off < 256; off <<= 1) {
        const int y = (tid >= off) ? tsum[tid - off] : 0;
        __syncthreads();
        x += (tid >= off) ? y : 0;
        tsum[tid] = x;
        __syncthreads();
    }
    if (tid < NB) { segStart[tid] = x - c; bucketCur[tid] = x - c; }
    if (tid == 0) segStart[NB] = E;
}

// ---------------- scatter: block-local counting sort -> contiguous runs ------
// rec.x = (dst&511)<<23 | src ; rec.y = weight bits
__global__ __launch_bounds__(256) void bucket_scatter_kernel(
    const int* __restrict__ ei, const float* __restrict__ ew,
    int* __restrict__ bucketCur, int2* __restrict__ rec, int E)
{
    __shared__ int2 srec[SC_EDGES];
    __shared__ unsigned char sbkt[SC_EDGES];
    __shared__ int cnt[256], scn[256], cur[256], gbase[256], tsum[256];
    const int tid = threadIdx.x;
    const int base = blockIdx.x * SC_EDGES;
    const int tot = min(SC_EDGES, E - base);
    cnt[tid] = 0;
    __syncthreads();

    int rdst[16], rsrc[16];
    float rw[16];
    #pragma unroll
    for (int k = 0; k < 16; ++k) {
        const int e = base + k * 256 + tid;
        rdst[k] = -1;
        if (e < E) {
            rdst[k] = ei[E + e];
            rsrc[k] = ei[e];
            rw[k]   = ew[e];
            atomicAdd(&cnt[rdst[k] >> BSH], 1);
        }
    }
    __syncthreads();

    // exclusive scan of per-bucket counts
    const int c = cnt[tid];
    tsum[tid] = c;
    __syncthreads();
    int x = c;
    for (int off = 1; off < 256; off <<= 1) {
        const int y = (tid >= off) ? tsum[tid - off] : 0;
        __syncthreads();
        x += (tid >= off) ? y : 0;
        tsum[tid] = x;
        __syncthreads();
    }
    scn[tid] = x - c;
    cur[tid] = x - c;
    gbase[tid] = (c > 0) ? atomicAdd(&bucketCur[tid], c) : 0;  // 1 atomic per bucket per block
    __syncthreads();

    #pragma unroll
    for (int k = 0; k < 16; ++k) {
        if (rdst[k] >= 0) {
            const int b = rdst[k] >> BSH;
            const int pos = atomicAdd(&cur[b], 1);
            srec[pos] = make_int2(
                (int)((((unsigned)rdst[k] & 511u) << 23) | (unsigned)rsrc[k]),
                __float_as_int(rw[k]));
            sbkt[pos] = (unsigned char)b;
        }
    }
    __syncthreads();

    // write grouped runs: contiguous, single-block-writer per run
    for (int i = tid; i < tot; i += 256) {
        const int b = sbkt[i];
        rec[gbase[b] + (i - scn[b])] = srec[i];
    }
}

// ---------------- per-bucket grouping (two-pass) + cursor emission -----------
__global__ __launch_bounds__(512) void sort_bucket_kernel(
    const int2* __restrict__ rec, const int* __restrict__ segStart,
    int2* __restrict__ out_rec, int* __restrict__ cursor, int N)
{
    __shared__ int cnt[512], scn[512], cur[512], tsum[512];
    const int b = blockIdx.x;
    const int beg = segStart[b];
    const int end = segStart[b + 1];
    const int tid = threadIdx.x;
    cnt[tid] = 0;
    __syncthreads();
    for (int i = beg + tid; i < end; i += 512)
        atomicAdd(&cnt[((unsigned)rec[i].x) >> 23], 1);
    __syncthreads();
    const int c = cnt[tid];
    tsum[tid] = c;
    __syncthreads();
    int x = c;
    for (int off = 1; off < 512; off <<= 1) {
        const int y = (tid >= off) ? tsum[tid - off] : 0;
        __syncthreads();
        x += (tid >= off) ? y : 0;
        tsum[tid] = x;
        __syncthreads();
    }
    scn[tid] = x - c;
    cur[tid] = x - c;
    const int dst = (b << BSH) + tid;
    if (dst < N) cursor[dst] = beg + x;   // inclusive end per dst
    __syncthreads();
    for (int i = beg + tid; i < end; i += 512) {
        const int2 r = rec[i];
        const int d = ((unsigned)r.x) >> 23;
        const int pos = beg + atomicAdd(&cur[d], 1);
        out_rec[pos] = make_int2(r.x & 0x7FFFFF, r.y);
    }
}

// ---------------- aggregate x: one wave per dst-PAIR, 16 gathers in flight ---
__global__ __launch_bounds__(256) void csr_agg_x_kernel(
    const int* __restrict__ cursor, const int2* __restrict__ rec,
    const __half* __restrict__ xh, __half* __restrict__ aggx,
    float* __restrict__ swv, int N)
{
    const int pr = blockIdx.x * 4 + (threadIdx.x >> 6);
    const int d0 = pr * 2;
    if (d0 >= N) return;
    const int d1 = d0 + 1;
    const int lane = threadIdx.x & 63;
    const int beg0 = (d0 == 0) ? 0 : cursor[d0 - 1];
    const int e0 = cursor[d0];
    const int e1 = (d1 < N) ? cursor[d1] : e0;   // empty if d1 invalid
    int p0 = beg0;
    int p1 = e0;                                  // beg1 == end0 (adjacent dsts)

    float2 a0 = make_float2(0.f, 0.f), a1 = make_float2(0.f, 0.f);
    float s0 = 0.f, s1 = 0.f;

    // joint main: 8 + 8 outstanding gathers (two independent chains)
    while (p0 + 8 <= e0 && p1 + 8 <= e1) {
        int2 r0[8], r1[8];
        #pragma unroll
        for (int j = 0; j < 8; ++j) { r0[j] = rec[p0 + j]; r1[j] = rec[p1 + j]; }
        __half2 v0[8], v1[8];
        #pragma unroll
        for (int j = 0; j < 8; ++j) {
            v0[j] = ((const __half2*)(xh + (size_t)r0[j].x * DIM))[lane];
            v1[j] = ((const __half2*)(xh + (size_t)r1[j].x * DIM))[lane];
        }
        #pragma unroll
        for (int j = 0; j < 8; ++j) {
            const float w0 = __int_as_float(r0[j].y);
            const float w1 = __int_as_float(r1[j].y);
            s0 += w0; s1 += w1;
            const float2 f0 = __half22float2(v0[j]);
            const float2 f1 = __half22float2(v1[j]);
            a0.x = fmaf(w0, f0.x, a0.x); a0.y = fmaf(w0, f0.y, a0.y);
            a1.x = fmaf(w1, f1.x, a1.x); a1.y = fmaf(w1, f1.y, a1.y);
        }
        p0 += 8; p1 += 8;
    }

    // joint masked tail: 4 + 4 (clamped index re-reads an L1-hot line; w=0 pads)
    while (p0 < e0 || p1 < e1) {
        const bool h0 = p0 < e0;
        const bool h1 = p1 < e1;
        int2 r0[4], r1[4];
        __half2 v0[4], v1[4];
        if (h0) {
            #pragma unroll
            for (int j = 0; j < 4; ++j) r0[j] = rec[min(p0 + j, e0 - 1)];
        }
        if (h1) {
            #pragma unroll
            for (int j = 0; j < 4; ++j) r1[j] = rec[min(p1 + j, e1 - 1)];
        }
        if (h0) {
            #pragma unroll
            for (int j = 0; j < 4; ++j)
                v0[j] = ((const __half2*)(xh + (size_t)r0[j].x * DIM))[lane];
        }
        if (h1) {
            #pragma unroll
            for (int j = 0; j < 4; ++j)
                v1[j] = ((const __half2*)(xh + (size_t)r1[j].x * DIM))[lane];
        }
        if (h0) {
            #pragma unroll
            for (int j = 0; j < 4; ++j) {
                const float w = (p0 + j < e0) ? __int_as_float(r0[j].y) : 0.f;
                s0 += w;
                const float2 f = __half22float2(v0[j]);
                a0.x = fmaf(w, f.x, a0.x); a0.y = fmaf(w, f.y, a0.y);
            }
            p0 += 4;
        }
        if (h1) {
            #pragma unroll
            for (int j = 0; j < 4; ++j) {
                const float w = (p1 + j < e1) ? __int_as_float(r1[j].y) : 0.f;
                s1 += w;
                const float2 f = __half22float2(v1[j]);
                a1.x = fmaf(w, f.x, a1.x); a1.y = fmaf(w, f.y, a1.y);
            }
            p1 += 4;
        }
    }

    ((__half2*)(aggx + (size_t)d0 * DIM))[lane] = __floats2half2_rn(a0.x, a0.y);
    if (lane == 0) swv[d0] = s0;
    if (d1 < N) {
        ((__half2*)(aggx + (size_t)d1 * DIM))[lane] = __floats2half2_rn(a1.x, a1.y);
        if (lane == 0) swv[d1] = s1;
    }
}

// ---------------- MFMA GEMM: D = W · X^T  (Wf staged in LDS) ----------------
__global__ __launch_bounds__(256) void gemm_mfma_kernel(
    const __half* __restrict__ X, const __half* __restrict__ Wf,
    const float* __restrict__ bias, const float* __restrict__ swv,
    __half* __restrict__ out_h, float* __restrict__ out_f, int mode, int N)
{
    __shared__ __half WfS[16384];   // 32 KB: whole layer's fragments
    const int tid = threadIdx.x;
    {
        const uint4* s4 = (const uint4*)Wf;
        uint4* d4 = (uint4*)WfS;
        #pragma unroll
        for (int i = 0; i < 8; ++i) d4[tid + i * 256] = s4[tid + i * 256];
    }
    __syncthreads();

    const int wave = tid >> 6;
    const int lane = tid & 63;
    const int g = lane >> 4;
    const int e = lane & 15;
    const int nbase = blockIdx.x * 128 + wave * 32;

    const int n0 = min(nbase + e, N - 1);
    const int n1 = min(nbase + 16 + e, N - 1);

    f32x4 acc[2][8];
    #pragma unroll
    for (int t = 0; t < 2; ++t)
        #pragma unroll
        for (int mt = 0; mt < 8; ++mt)
            acc[t][mt] = (f32x4){0.f, 0.f, 0.f, 0.f};

    const f16x8* Xr0 = (const f16x8*)(X + (size_t)n0 * DIM + g * 8);
    const f16x8* Xr1 = (const f16x8*)(X + (size_t)n1 * DIM + g * 8);
    const f16x8* Wp  = (const f16x8*)WfS;

    #pragma unroll
    for (int s = 0; s < 4; ++s) {
        const f16x8 b0 = Xr0[s * 4];
        const f16x8 b1 = Xr1[s * 4];
        #pragma unroll
        for (int mt = 0; mt < 8; ++mt) {
            const f16x8 a = Wp[(s * 8 + mt) * 64 + lane];
            acc[0][mt] = __builtin_amdgcn_mfma_f32_16x16x32_f16(a, b0, acc[0][mt], 0, 0, 0);
            acc[1][mt] = __builtin_amdgcn_mfma_f32_16x16x32_f16(a, b1, acc[1][mt], 0, 0, 0);
        }
    }

    #pragma unroll
    for (int t = 0; t < 2; ++t) {
        const int node = nbase + t * 16 + e;
        if (node >= N) continue;
        const float sw = swv[node];
        #pragma unroll
        for (int mt = 0; mt < 8; ++mt) {
            const int ch0 = mt * 16 + g * 4;
            const float4 bv = *(const float4*)(bias + ch0);
            float4 v;
            v.x = fmaxf(fmaf(sw, bv.x, acc[t][mt][0]), 0.f);
            v.y = fmaxf(fmaf(sw, bv.y, acc[t][mt][1]), 0.f);
            v.z = fmaxf(fmaf(sw, bv.z, acc[t][mt][2]), 0.f);
            v.w = fmaxf(fmaf(sw, bv.w, acc[t][mt][3]), 0.f);
            if (mode == 0) {
                const __half2 h01 = __floats2half2_rn(v.x, v.y);
                const __half2 h23 = __floats2half2_rn(v.z, v.w);
                uint2 u;
                u.x = *(const unsigned*)&h01;
                u.y = *(const unsigned*)&h23;
                *(uint2*)(out_h + (size_t)node * DIM + ch0) = u;
            } else {
                *(float4*)(out_f + (size_t)node * DIM + ch0) = v;
            }
        }
    }
}

extern "C" void kernel_launch(void* const* d_in, const int* in_sizes, int n_in,
                              void* d_out, int out_size, void* d_ws, size_t ws_size,
                              hipStream_t stream)
{
    const int*   ei        = (const int*)d_in[0];
    const float* ew        = (const float*)d_in[1];
    const float* row_embed = (const float*)d_in[2];
    const float* col_embed = (const float*)d_in[3];
    const float* W         = (const float*)d_in[4];
    const float* bias      = (const float*)d_in[5];

    const int E     = in_sizes[1];
    const int nrows = in_sizes[2] / DIM;
    const int ncols = in_sizes[3] / DIM;
    const int N     = nrows + ncols;
    const int L     = in_sizes[5] / DIM;
    const int NB    = (N + 511) >> BSH;   // <= 256 required (N <= 131072)

    size_t off = 0;
    auto alloc = [&](size_t bytes) -> char* {
        char* p = (char*)d_ws + off;
        off = (off + bytes + 15) & ~(size_t)15;
        return p;
    };
    __half* Wf        = (__half*)alloc((size_t)L * 16384 * sizeof(__half));
    __half* xh        = (__half*)alloc((size_t)N * DIM * sizeof(__half));
    __half* aggx      = (__half*)alloc((size_t)N * DIM * sizeof(__half));
    float*  swv       = (float*) alloc((size_t)N * sizeof(float));
    int*    cursor    = (int*)   alloc((size_t)NB * 512 * sizeof(int));
    int*    hist      = (int*)   alloc(256 * sizeof(int));
    int*    segStart  = (int*)   alloc((size_t)(NB + 1) * sizeof(int));
    int*    bucketCur = (int*)   alloc(256 * sizeof(int));
    int2*   rec       = (int2*)  alloc((size_t)E * sizeof(int2));

    int2* out_rec = (int2*)d_out;   // d_out is free until the last GEMM

    pack_wf_kernel<<<L * 32, 64, 0, stream>>>(W, Wf);
    convert_x0_kernel<<<(N * (DIM / 4) + 255) / 256, 256, 0, stream>>>(
        row_embed, col_embed, xh, nrows, N);

    const int eb = (E + SC_EDGES - 1) / SC_EDGES;
    zero_i_kernel<<<1, 256, 0, stream>>>(hist, 256);
    hist_block_kernel<<<eb, 256, 0, stream>>>(ei, hist, E);
    scan_nb_kernel<<<1, 256, 0, stream>>>(hist, segStart, bucketCur, NB, E);
    bucket_scatter_kernel<<<eb, 256, 0, stream>>>(ei, ew, bucketCur, rec, E);
    sort_bucket_kernel<<<NB, 512, 0, stream>>>(rec, segStart, out_rec, cursor, N);

    const int npairs = (N + 1) / 2;
    const int agg_blocks  = (npairs + 3) / 4;
    const int gemm_blocks = (N + 127) / 128;

    for (int l = 0; l < L; ++l) {
        csr_agg_x_kernel<<<agg_blocks, 256, 0, stream>>>(cursor, out_rec, xh, aggx, swv, N);
        const int last = (l == L - 1);
        gemm_mfma_kernel<<<gemm_blocks, 256, 0, stream>>>(
            aggx, Wf + (size_t)l * 16384, bias + (size_t)l * DIM, swv,
            xh, (float*)d_out, last ? 1 : 0, N);
    }
}

// Round 16
// 318.193 us; speedup vs baseline: 1.0730x; 1.0730x over previous
//
#include <hip/hip_runtime.h>
#include <hip/hip_fp16.h>

#define DIM 128
#define BSH 9              // dsts per bucket = 512  (NB = 196 for N=100032)
#define SC_EDGES 4096      // edges per scatter/hist block

typedef _Float16 f16x8 __attribute__((ext_vector_type(8)));
typedef float f32x4 __attribute__((ext_vector_type(4)));

// ---------------- pack W into MFMA A-fragments ----------------
// Wf[b][lane][j] = W[l][ mt*16 + (lane&15) ][ s*32 + (lane>>4)*8 + j ],  b=(l*4+s)*8+mt
__global__ __launch_bounds__(64) void pack_wf_kernel(
    const float* __restrict__ W, __half* __restrict__ Wf)
{
    const int b = blockIdx.x;
    const int mt = b & 7;
    const int s  = (b >> 3) & 3;
    const int l  = b >> 5;
    const int lane = threadIdx.x;
    const int c  = mt * 16 + (lane & 15);
    const int k0 = s * 32 + (lane >> 4) * 8;
    const float* wr = W + ((size_t)l << 14) + c * DIM + k0;
    __half* dp = Wf + ((size_t)b * 64 + lane) * 8;
    #pragma unroll
    for (int j = 0; j < 8; ++j) dp[j] = __float2half(wr[j]);
}

// ---------------- x0 = concat(row_embed, col_embed) -> fp16 ----------------
__global__ __launch_bounds__(256) void convert_x0_kernel(
    const float* __restrict__ xa, const float* __restrict__ xb,
    __half* __restrict__ xh, int nrows_a, int N)
{
    const int i = blockIdx.x * 256 + threadIdx.x;
    if (i >= N * (DIM / 4)) return;
    const int row = i >> 5;
    const int g = i & 31;
    const float* sp = (row < nrows_a) ? xa + (size_t)row * DIM
                                      : xb + (size_t)(row - nrows_a) * DIM;
    const float4 v = ((const float4*)sp)[g];
    __half2* dp = (__half2*)(xh + (size_t)row * DIM + g * 4);
    dp[0] = __floats2half2_rn(v.x, v.y);
    dp[1] = __floats2half2_rn(v.z, v.w);
}

__global__ __launch_bounds__(256) void zero_i_kernel(int* __restrict__ p, int n)
{
    const int i = blockIdx.x * 256 + threadIdx.x;
    if (i < n) p[i] = 0;
}

// ---------------- bucket histogram: LDS pre-aggregation ----------------------
__global__ __launch_bounds__(256) void hist_block_kernel(
    const int* __restrict__ ei, int* __restrict__ hist, int E)
{
    __shared__ int cnt[256];
    const int tid = threadIdx.x;
    cnt[tid] = 0;
    __syncthreads();
    const int base = blockIdx.x * SC_EDGES;
    #pragma unroll
    for (int k = 0; k < 16; ++k) {
        const int e = base + k * 256 + tid;
        if (e < E) atomicAdd(&cnt[ei[E + e] >> BSH], 1);
    }
    __syncthreads();
    if (cnt[tid] > 0) atomicAdd(&hist[tid], cnt[tid]);
}

// ---------------- exclusive scan of NB (<=256) bucket counts -----------------
__global__ __launch_bounds__(256) void scan_nb_kernel(
    const int* __restrict__ hist, int* __restrict__ segStart,
    int* __restrict__ bucketCur, int NB, int E)
{
    __shared__ int tsum[256];
    const int tid = threadIdx.x;
    const int c = (tid < NB) ? hist[tid] : 0;
    tsum[tid] = c;
    __syncthreads();
    int x = c;
    for (int off = 1; off < 256; off <<= 1) {
        const int y = (tid >= off) ? tsum[tid - off] : 0;
        __syncthreads();
        x += (tid >= off) ? y : 0;
        tsum[tid] = x;
        __syncthreads();
    }
    if (tid < NB) { segStart[tid] = x - c; bucketCur[tid] = x - c; }
    if (tid == 0) segStart[NB] = E;
}

// ---------------- scatter: block-local counting sort -> contiguous runs ------
// rec.x = (dst&511)<<23 | src ; rec.y = weight bits
__global__ __launch_bounds__(256) void bucket_scatter_kernel(
    const int* __restrict__ ei, const float* __restrict__ ew,
    int* __restrict__ bucketCur, int2* __restrict__ rec, int E)
{
    __shared__ int2 srec[SC_EDGES];
    __shared__ unsigned char sbkt[SC_EDGES];
    __shared__ int cnt[256], scn[256], cur[256], gbase[256], tsum[256];
    const int tid = threadIdx.x;
    const int base = blockIdx.x * SC_EDGES;
    const int tot = min(SC_EDGES, E - base);
    cnt[tid] = 0;
    __syncthreads();

    int rdst[16], rsrc[16];
    float rw[16];
    #pragma unroll
    for (int k = 0; k < 16; ++k) {
        const int e = base + k * 256 + tid;
        rdst[k] = -1;
        if (e < E) {
            rdst[k] = ei[E + e];
            rsrc[k] = ei[e];
            rw[k]   = ew[e];
            atomicAdd(&cnt[rdst[k] >> BSH], 1);
        }
    }
    __syncthreads();

    // exclusive scan of per-bucket counts
    const int c = cnt[tid];
    tsum[tid] = c;
    __syncthreads();
    int x = c;
    for (int off = 1; off < 256; off <<= 1) {
        const int y = (tid >= off) ? tsum[tid - off] : 0;
        __syncthreads();
        x += (tid >= off) ? y : 0;
        tsum[tid] = x;
        __syncthreads();
    }
    scn[tid] = x - c;
    cur[tid] = x - c;
    gbase[tid] = (c > 0) ? atomicAdd(&bucketCur[tid], c) : 0;  // 1 atomic per bucket per block
    __syncthreads();

    #pragma unroll
    for (int k = 0; k < 16; ++k) {
        if (rdst[k] >= 0) {
            const int b = rdst[k] >> BSH;
            const int pos = atomicAdd(&cur[b], 1);
            srec[pos] = make_int2(
                (int)((((unsigned)rdst[k] & 511u) << 23) | (unsigned)rsrc[k]),
                __float_as_int(rw[k]));
            sbkt[pos] = (unsigned char)b;
        }
    }
    __syncthreads();

    // write grouped runs: contiguous, single-block-writer per run
    for (int i = tid; i < tot; i += 256) {
        const int b = sbkt[i];
        rec[gbase[b] + (i - scn[b])] = srec[i];
    }
}

// ---------------- per-bucket grouping (two-pass) + cursor emission -----------
__global__ __launch_bounds__(512) void sort_bucket_kernel(
    const int2* __restrict__ rec, const int* __restrict__ segStart,
    int2* __restrict__ out_rec, int* __restrict__ cursor, int N)
{
    __shared__ int cnt[512], scn[512], cur[512], tsum[512];
    const int b = blockIdx.x;
    const int beg = segStart[b];
    const int end = segStart[b + 1];
    const int tid = threadIdx.x;
    cnt[tid] = 0;
    __syncthreads();
    for (int i = beg + tid; i < end; i += 512)
        atomicAdd(&cnt[((unsigned)rec[i].x) >> 23], 1);
    __syncthreads();
    const int c = cnt[tid];
    tsum[tid] = c;
    __syncthreads();
    int x = c;
    for (int off = 1; off < 512; off <<= 1) {
        const int y = (tid >= off) ? tsum[tid - off] : 0;
        __syncthreads();
        x += (tid >= off) ? y : 0;
        tsum[tid] = x;
        __syncthreads();
    }
    scn[tid] = x - c;
    cur[tid] = x - c;
    const int dst = (b << BSH) + tid;
    if (dst < N) cursor[dst] = beg + x;   // inclusive end per dst
    __syncthreads();
    for (int i = beg + tid; i < end; i += 512) {
        const int2 r = rec[i];
        const int d = ((unsigned)r.x) >> 23;
        const int pos = beg + atomicAdd(&cur[d], 1);
        out_rec[pos] = make_int2(r.x & 0x7FFFFF, r.y);
    }
}

// ---------------- aggregate x: one wave per dst, 16-deep main + geo tail -----
// beg/end forced to SGPRs (readfirstlane) -> rec loads scalarize (s_load),
// freeing VGPRs and decoupling rec fetch (lgkmcnt) from gathers (vmcnt).
__global__ __launch_bounds__(256) void csr_agg_x_kernel(
    const int* __restrict__ cursor, const int2* __restrict__ rec,
    const __half* __restrict__ xh, __half* __restrict__ aggx,
    float* __restrict__ swv, int N)
{
    const int dst = blockIdx.x * 4 + (threadIdx.x >> 6);
    if (dst >= N) return;
    const int lane = threadIdx.x & 63;
    const int end = __builtin_amdgcn_readfirstlane(cursor[dst]);
    const int beg = __builtin_amdgcn_readfirstlane((dst == 0) ? 0 : cursor[dst - 1]);
    float2 acc = make_float2(0.f, 0.f);
    float sw = 0.f;
    int p = beg;

    // main: 16 records per iteration, all 16 gathers in flight
    for (; p + 16 <= end; p += 16) {
        int2 r[16];
        #pragma unroll
        for (int j = 0; j < 16; ++j) r[j] = rec[p + j];
        __half2 v[16];
        #pragma unroll
        for (int j = 0; j < 16; ++j)
            v[j] = ((const __half2*)(xh + (size_t)r[j].x * DIM))[lane];
        #pragma unroll
        for (int j = 0; j < 16; ++j) {
            const float w = __int_as_float(r[j].y);
            sw += w;
            const float2 f = __half22float2(v[j]);
            acc.x = fmaf(w, f.x, acc.x);
            acc.y = fmaf(w, f.y, acc.y);
        }
    }
    if (p + 8 <= end) {
        int2 r[8];
        #pragma unroll
        for (int j = 0; j < 8; ++j) r[j] = rec[p + j];
        __half2 v[8];
        #pragma unroll
        for (int j = 0; j < 8; ++j)
            v[j] = ((const __half2*)(xh + (size_t)r[j].x * DIM))[lane];
        #pragma unroll
        for (int j = 0; j < 8; ++j) {
            const float w = __int_as_float(r[j].y);
            sw += w;
            const float2 f = __half22float2(v[j]);
            acc.x = fmaf(w, f.x, acc.x);
            acc.y = fmaf(w, f.y, acc.y);
        }
        p += 8;
    }
    if (p + 4 <= end) {
        int2 r[4];
        #pragma unroll
        for (int j = 0; j < 4; ++j) r[j] = rec[p + j];
        __half2 v[4];
        #pragma unroll
        for (int j = 0; j < 4; ++j)
            v[j] = ((const __half2*)(xh + (size_t)r[j].x * DIM))[lane];
        #pragma unroll
        for (int j = 0; j < 4; ++j) {
            const float w = __int_as_float(r[j].y);
            sw += w;
            const float2 f = __half22float2(v[j]);
            acc.x = fmaf(w, f.x, acc.x);
            acc.y = fmaf(w, f.y, acc.y);
        }
        p += 4;
    }
    if (p + 2 <= end) {
        int2 r0 = rec[p], r1 = rec[p + 1];
        __half2 v0 = ((const __half2*)(xh + (size_t)r0.x * DIM))[lane];
        __half2 v1 = ((const __half2*)(xh + (size_t)r1.x * DIM))[lane];
        const float w0 = __int_as_float(r0.y);
        const float w1 = __int_as_float(r1.y);
        sw += w0 + w1;
        float2 f0 = __half22float2(v0);
        float2 f1 = __half22float2(v1);
        acc.x = fmaf(w0, f0.x, acc.x); acc.y = fmaf(w0, f0.y, acc.y);
        acc.x = fmaf(w1, f1.x, acc.x); acc.y = fmaf(w1, f1.y, acc.y);
        p += 2;
    }
    if (p < end) {
        const int2 r0 = rec[p];
        const __half2 v0 = ((const __half2*)(xh + (size_t)r0.x * DIM))[lane];
        const float w0 = __int_as_float(r0.y);
        sw += w0;
        const float2 f = __half22float2(v0);
        acc.x = fmaf(w0, f.x, acc.x);
        acc.y = fmaf(w0, f.y, acc.y);
    }
    ((__half2*)(aggx + (size_t)dst * DIM))[lane] = __floats2half2_rn(acc.x, acc.y);
    if (lane == 0) swv[dst] = sw;
}

// ---------------- MFMA GEMM: D = W · X^T  (Wf staged in LDS) ----------------
__global__ __launch_bounds__(256) void gemm_mfma_kernel(
    const __half* __restrict__ X, const __half* __restrict__ Wf,
    const float* __restrict__ bias, const float* __restrict__ swv,
    __half* __restrict__ out_h, float* __restrict__ out_f, int mode, int N)
{
    __shared__ __half WfS[16384];   // 32 KB: whole layer's fragments
    const int tid = threadIdx.x;
    {
        const uint4* s4 = (const uint4*)Wf;
        uint4* d4 = (uint4*)WfS;
        #pragma unroll
        for (int i = 0; i < 8; ++i) d4[tid + i * 256] = s4[tid + i * 256];
    }
    __syncthreads();

    const int wave = tid >> 6;
    const int lane = tid & 63;
    const int g = lane >> 4;
    const int e = lane & 15;
    const int nbase = blockIdx.x * 128 + wave * 32;

    const int n0 = min(nbase + e, N - 1);
    const int n1 = min(nbase + 16 + e, N - 1);

    f32x4 acc[2][8];
    #pragma unroll
    for (int t = 0; t < 2; ++t)
        #pragma unroll
        for (int mt = 0; mt < 8; ++mt)
            acc[t][mt] = (f32x4){0.f, 0.f, 0.f, 0.f};

    const f16x8* Xr0 = (const f16x8*)(X + (size_t)n0 * DIM + g * 8);
    const f16x8* Xr1 = (const f16x8*)(X + (size_t)n1 * DIM + g * 8);
    const f16x8* Wp  = (const f16x8*)WfS;

    #pragma unroll
    for (int s = 0; s < 4; ++s) {
        const f16x8 b0 = Xr0[s * 4];
        const f16x8 b1 = Xr1[s * 4];
        #pragma unroll
        for (int mt = 0; mt < 8; ++mt) {
            const f16x8 a = Wp[(s * 8 + mt) * 64 + lane];
            acc[0][mt] = __builtin_amdgcn_mfma_f32_16x16x32_f16(a, b0, acc[0][mt], 0, 0, 0);
            acc[1][mt] = __builtin_amdgcn_mfma_f32_16x16x32_f16(a, b1, acc[1][mt], 0, 0, 0);
        }
    }

    #pragma unroll
    for (int t = 0; t < 2; ++t) {
        const int node = nbase + t * 16 + e;
        if (node >= N) continue;
        const float sw = swv[node];
        #pragma unroll
        for (int mt = 0; mt < 8; ++mt) {
            const int ch0 = mt * 16 + g * 4;
            const float4 bv = *(const float4*)(bias + ch0);
            float4 v;
            v.x = fmaxf(fmaf(sw, bv.x, acc[t][mt][0]), 0.f);
            v.y = fmaxf(fmaf(sw, bv.y, acc[t][mt][1]), 0.f);
            v.z = fmaxf(fmaf(sw, bv.z, acc[t][mt][2]), 0.f);
            v.w = fmaxf(fmaf(sw, bv.w, acc[t][mt][3]), 0.f);
            if (mode == 0) {
                const __half2 h01 = __floats2half2_rn(v.x, v.y);
                const __half2 h23 = __floats2half2_rn(v.z, v.w);
                uint2 u;
                u.x = *(const unsigned*)&h01;
                u.y = *(const unsigned*)&h23;
                *(uint2*)(out_h + (size_t)node * DIM + ch0) = u;
            } else {
                *(float4*)(out_f + (size_t)node * DIM + ch0) = v;
            }
        }
    }
}

extern "C" void kernel_launch(void* const* d_in, const int* in_sizes, int n_in,
                              void* d_out, int out_size, void* d_ws, size_t ws_size,
                              hipStream_t stream)
{
    const int*   ei        = (const int*)d_in[0];
    const float* ew        = (const float*)d_in[1];
    const float* row_embed = (const float*)d_in[2];
    const float* col_embed = (const float*)d_in[3];
    const float* W         = (const float*)d_in[4];
    const float* bias      = (const float*)d_in[5];

    const int E     = in_sizes[1];
    const int nrows = in_sizes[2] / DIM;
    const int ncols = in_sizes[3] / DIM;
    const int N     = nrows + ncols;
    const int L     = in_sizes[5] / DIM;
    const int NB    = (N + 511) >> BSH;   // <= 256 required (N <= 131072)

    size_t off = 0;
    auto alloc = [&](size_t bytes) -> char* {
        char* p = (char*)d_ws + off;
        off = (off + bytes + 15) & ~(size_t)15;
        return p;
    };
    __half* Wf        = (__half*)alloc((size_t)L * 16384 * sizeof(__half));
    __half* xh        = (__half*)alloc((size_t)N * DIM * sizeof(__half));
    __half* aggx      = (__half*)alloc((size_t)N * DIM * sizeof(__half));
    float*  swv       = (float*) alloc((size_t)N * sizeof(float));
    int*    cursor    = (int*)   alloc((size_t)NB * 512 * sizeof(int));
    int*    hist      = (int*)   alloc(256 * sizeof(int));
    int*    segStart  = (int*)   alloc((size_t)(NB + 1) * sizeof(int));
    int*    bucketCur = (int*)   alloc(256 * sizeof(int));
    int2*   rec       = (int2*)  alloc((size_t)E * sizeof(int2));

    int2* out_rec = (int2*)d_out;   // d_out is free until the last GEMM

    pack_wf_kernel<<<L * 32, 64, 0, stream>>>(W, Wf);
    convert_x0_kernel<<<(N * (DIM / 4) + 255) / 256, 256, 0, stream>>>(
        row_embed, col_embed, xh, nrows, N);

    const int eb = (E + SC_EDGES - 1) / SC_EDGES;
    zero_i_kernel<<<1, 256, 0, stream>>>(hist, 256);
    hist_block_kernel<<<eb, 256, 0, stream>>>(ei, hist, E);
    scan_nb_kernel<<<1, 256, 0, stream>>>(hist, segStart, bucketCur, NB, E);
    bucket_scatter_kernel<<<eb, 256, 0, stream>>>(ei, ew, bucketCur, rec, E);
    sort_bucket_kernel<<<NB, 512, 0, stream>>>(rec, segStart, out_rec, cursor, N);

    const int agg_blocks  = (N + 3) / 4;
    const int gemm_blocks = (N + 127) / 128;

    for (int l = 0; l < L; ++l) {
        csr_agg_x_kernel<<<agg_blocks, 256, 0, stream>>>(cursor, out_rec, xh, aggx, swv, N);
        const int last = (l == L - 1);
        gemm_mfma_kernel<<<gemm_blocks, 256, 0, stream>>>(
            aggx, Wf + (size_t)l * 16384, bias + (size_t)l * DIM, swv,
            xh, (float*)d_out, last ? 1 : 0, N);
    }
}